// Round 9
// baseline (61.632 us; speedup 1.0000x reference)
//
#include <hip/hip_runtime.h>

// MoE gate: logits = x @ W^T (x:[16384,2048] f32, W:[64,2048] f32),
// softmax over 64 experts, top-8 -> weights f32 + indices stored as f32.
//
// R9: cross-block K-split + L1-shared W stream.
//  pack_w:  W -> packed bf16 H/M/L fragment triples (768KB, L2-hot).
//  ksplit:  grid 256 = 64 token-groups(256 tok) x 4 K-quarters; 8 waves all
//           read the SAME W-quarter stream (L1 dedupe: W misses 196->49MB).
//           Wave-private LDS x staging (NT-hinted, keeps W in L1), R8's
//           HW-proven barrier-free SLICE schedule + phase-lock s_barrier
//           every 4 slices. Partial logits -> d_ws.
//  combine: deterministic 4-way sum + fused softmax/top-8.
// Total L1-miss traffic ~214MB vs R8's 324MB (6.3 TB/s miss-fill wall).

typedef __attribute__((ext_vector_type(8))) short short8;
typedef __attribute__((ext_vector_type(16))) float f32x16;
typedef __attribute__((ext_vector_type(4))) float f32x4;
typedef __attribute__((ext_vector_type(4))) unsigned int u32x4;

#define NT    16384
#define DIMK  2048
#define NE    64
#define TOPKK 8
#define WPK_BYTES 786432
#define PL_BYTES  (4 * NT * NE * 4)           // 16777216
#define WS_NEED   (WPK_BYTES + PL_BYTES)      // 17563648

union U4S8 { unsigned int u[4]; short8 s; u32x4 v; };

__device__ __forceinline__ short8 as_s8(u32x4 v) { U4S8 t; t.v = v; return t.s; }

// Bit-exact 3-way bf16 split of 8 f32 (truncation; subtractions exact).
__device__ __forceinline__ void split3(const float4 a, const float4 b,
                                       short8& H, short8& M, short8& L) {
    const float f[8] = {a.x, a.y, a.z, a.w, b.x, b.y, b.z, b.w};
    U4S8 uh, um, ul;
#pragma unroll
    for (int p = 0; p < 4; ++p) {
        const float f0 = f[2 * p], f1 = f[2 * p + 1];
        const unsigned int t0 = __float_as_uint(f0) & 0xFFFF0000u;
        const unsigned int t1 = __float_as_uint(f1) & 0xFFFF0000u;
        uh.u[p] = (t0 >> 16) | t1;
        const float r0 = f0 - __uint_as_float(t0);
        const float r1 = f1 - __uint_as_float(t1);
        const unsigned int v0 = __float_as_uint(r0) & 0xFFFF0000u;
        const unsigned int v1 = __float_as_uint(r1) & 0xFFFF0000u;
        um.u[p] = (v0 >> 16) | v1;
        const float s0 = r0 - __uint_as_float(v0);
        const float s1 = r1 - __uint_as_float(v1);
        ul.u[p] = (__float_as_uint(s0) >> 16) | (__float_as_uint(s1) & 0xFFFF0000u);
    }
    H = uh.s; M = um.s; L = ul.s;
}

__device__ __forceinline__ f32x16 mfma6w(short8 ah, short8 am, short8 al,
                                         short8 bh, short8 bm, short8 bl,
                                         f32x16 c) {
    c = __builtin_amdgcn_mfma_f32_32x32x16_bf16(ah, bh, c, 0, 0, 0);
    c = __builtin_amdgcn_mfma_f32_32x32x16_bf16(ah, bm, c, 0, 0, 0);
    c = __builtin_amdgcn_mfma_f32_32x32x16_bf16(am, bh, c, 0, 0, 0);
    c = __builtin_amdgcn_mfma_f32_32x32x16_bf16(ah, bl, c, 0, 0, 0);
    c = __builtin_amdgcn_mfma_f32_32x32x16_bf16(am, bm, c, 0, 0, 0);
    c = __builtin_amdgcn_mfma_f32_32x32x16_bf16(al, bh, c, 0, 0, 0);
    return c;
}

// ---- pack W -> 32x32 B-fragment-ordered bf16 triples (verified R5/R7/R8) --
__global__ __launch_bounds__(64) void pack_w_kernel(
    const float* __restrict__ W, short* __restrict__ wpk)
{
    const int b  = blockIdx.x;          // 256 = c*8 + fg, fg = 2*s16 + n32
    const int c  = b >> 3, fg = b & 7;
    const int s  = fg >> 1, n32 = fg & 1;
    const int l  = threadIdx.x;
    const float* g = W + (size_t)(32 * n32 + (l & 31)) * DIMK
                       + 64 * c + 16 * s + 8 * (l >> 5);
    const float4 lo = *(const float4*)g;
    const float4 hi = *(const float4*)(g + 4);
    short8 H, M, L;
    split3(lo, hi, H, M, L);
    const size_t base = ((size_t)(c * 8 + fg) * 3) * 512 + l * 8;
    *(short8*)(wpk + base)        = H;
    *(short8*)(wpk + base + 512)  = M;
    *(short8*)(wpk + base + 1024) = L;
}

#define WLOAD3(d0, d1, d2, p)                                                 \
    asm volatile("global_load_dwordx4 %0, %3, off\n\t"                        \
                 "global_load_dwordx4 %1, %3, off offset:1024\n\t"            \
                 "global_load_dwordx4 %2, %3, off offset:2048"                \
                 : "=&v"(d0), "=&v"(d1), "=&v"(d2) : "v"(p))
#define WAITN(n) do {                                                         \
    asm volatile("s_waitcnt vmcnt(" #n ")" ::: "memory");                     \
    __builtin_amdgcn_sched_barrier(0);                                        \
} while (0)

__device__ __forceinline__ void async16nt(void* lds, const void* gp) {
    __builtin_amdgcn_global_load_lds(
        (const __attribute__((address_space(1))) unsigned int*)gp,
        (__attribute__((address_space(3))) unsigned int*)lds, 16, 0, 2 /*NT*/);
}

// ================= R9 main: K-split, shared W stream =================
__global__ __launch_bounds__(512, 1) void gate_ksplit_kernel(
    const float* __restrict__ x, const short* __restrict__ wpk,
    float* __restrict__ pl)
{
    __shared__ __align__(16) char smem[8 * 3 * 4096];   // wave-private staging

    const int tid = threadIdx.x;
    const int w   = tid >> 6;
    const int l   = tid & 63;
    const int r31 = l & 31;
    const int l5  = l >> 5;
    const int tg  = blockIdx.x >> 2;     // token group (256 tokens)
    const int kq  = blockIdx.x & 3;      // K quarter
    const int bt0 = tg * 256;
    const int tokbase = bt0 + 32 * w;    // wave's 32 tokens

    char* wbase = smem + w * 12288;
    const int swr = (r31 & 7) ^ (((r31 >> 3) & 3) << 1);
    const int srow = l >> 3;
    const int sg0  = (l & 7) ^ srow;
    const float* xrow0 = x + (size_t)(tokbase + srow) * DIMK + kq * 512;

#define STAGE_CHUNK(k) do {                                                   \
    _Pragma("unroll")                                                         \
    for (int i = 0; i < 4; ++i) {                                             \
        const float* gsrc = xrow0 + (size_t)(8 * i) * DIMK + (k) * 32         \
                          + ((sg0 ^ (2 * i)) << 2);                           \
        async16nt(wbase + ((k) % 3) * 4096 + i * 1024, gsrc);                 \
    }                                                                         \
} while (0)

    // ALL waves share this stream (L1 dedupe is the point of R9)
    const short* wq0 = wpk + (size_t)kq * 98304 + l * 8;
    const short* wq1 = wq0 + 1536;

    f32x16 acc0, acc1;
#pragma unroll
    for (int i = 0; i < 16; ++i) { acc0[i] = 0.f; acc1[i] = 0.f; }

    u32x4 w0v[4][3], w1v[4][3];

    STAGE_CHUNK(0);
    STAGE_CHUNK(1);
    STAGE_CHUNK(2);
    WLOAD3(w0v[0][0], w0v[0][1], w0v[0][2], wq0); wq0 += 3072;
    WLOAD3(w1v[0][0], w1v[0][1], w1v[0][2], wq1); wq1 += 3072;
    WLOAD3(w0v[1][0], w0v[1][1], w0v[1][2], wq0); wq0 += 3072;
    WLOAD3(w1v[1][0], w1v[1][1], w1v[1][2], wq1); wq1 += 3072;
    WLOAD3(w0v[2][0], w0v[2][1], w0v[2][2], wq0); wq0 += 3072;
    WLOAD3(w1v[2][0], w1v[2][1], w1v[2][2], wq1); wq1 += 3072;

    // R8's HW-proven schedule, verbatim literals.
#define SLICE(t) do {                                                         \
    if ((t) <= 28) {                                                          \
        WLOAD3(w0v[((t)+3)&3][0], w0v[((t)+3)&3][1], w0v[((t)+3)&3][2], wq0); \
        wq0 += 3072;                                                          \
        WLOAD3(w1v[((t)+3)&3][0], w1v[((t)+3)&3][1], w1v[((t)+3)&3][2], wq1); \
        wq1 += 3072;                                                          \
    }                                                                         \
    if ((t) <= 1)            WAITN(18);                                       \
    else if ((t) == 29)      WAITN(12);                                       \
    else if ((t) == 30)      WAITN(6);                                        \
    else if ((t) == 31)      WAITN(0);                                        \
    else if (((t) & 1) || (t) == 2 || (t) == 28) WAITN(22);                   \
    else                     WAITN(26);                                       \
    {                                                                         \
        const char* xb = wbase + (((t) >> 1) % 3) * 4096;                     \
        const float4 a0 = *(const float4*)(xb + r31 * 128 +                   \
            (((((t) & 1) * 4 + 2 * l5 + 0) ^ swr) << 4));                     \
        const float4 a1 = *(const float4*)(xb + r31 * 128 +                   \
            (((((t) & 1) * 4 + 2 * l5 + 1) ^ swr) << 4));                     \
        short8 H, M, L;                                                       \
        split3(a0, a1, H, M, L);                                              \
        acc0 = mfma6w(H, M, L, as_s8(w0v[(t)&3][0]), as_s8(w0v[(t)&3][1]),    \
                      as_s8(w0v[(t)&3][2]), acc0);                            \
        acc1 = mfma6w(H, M, L, as_s8(w1v[(t)&3][0]), as_s8(w1v[(t)&3][1]),    \
                      as_s8(w1v[(t)&3][2]), acc1);                            \
    }                                                                         \
    if (((t) & 1) && (t) <= 25) STAGE_CHUNK(((t) + 5) >> 1);                  \
} while (0)

#define PBAR() __builtin_amdgcn_s_barrier()   // phase-lock only (no LDS dep)

    SLICE(0);  SLICE(1);  SLICE(2);  SLICE(3);  PBAR();
    SLICE(4);  SLICE(5);  SLICE(6);  SLICE(7);  PBAR();
    SLICE(8);  SLICE(9);  SLICE(10); SLICE(11); PBAR();
    SLICE(12); SLICE(13); SLICE(14); SLICE(15); PBAR();
    SLICE(16); SLICE(17); SLICE(18); SLICE(19); PBAR();
    SLICE(20); SLICE(21); SLICE(22); SLICE(23); PBAR();
    SLICE(24); SLICE(25); SLICE(26); SLICE(27); PBAR();
    SLICE(28); SLICE(29); SLICE(30); SLICE(31);

    // partial logits -> pl[kq][NT][64]; C/D: col=l&31, row=(r&3)+8*(r>>2)+4*l5
    float* base0 = pl + ((size_t)kq * NT + tokbase) * NE;
#pragma unroll
    for (int r = 0; r < 16; ++r) {
        const int rowc = (r & 3) + 8 * (r >> 2) + 4 * l5;
        base0[rowc * NE + r31]      = acc0[r];
        base0[rowc * NE + 32 + r31] = acc1[r];
    }
#undef SLICE
#undef STAGE_CHUNK
#undef PBAR
}

// ================= combine: sum partials + softmax + top-8 =================
__global__ __launch_bounds__(64) void gate_combine_kernel(
    const float* __restrict__ pl, float* __restrict__ out)
{
    const int g = blockIdx.x * 64 + threadIdx.x;   // token
    const f32x4* p0 = (const f32x4*)(pl + (size_t)g * NE);
    const f32x4* p1 = (const f32x4*)(pl + ((size_t)NT + g) * NE);
    const f32x4* p2 = (const f32x4*)(pl + ((size_t)2 * NT + g) * NE);
    const f32x4* p3 = (const f32x4*)(pl + ((size_t)3 * NT + g) * NE);

    f32x4 row[16];
#pragma unroll
    for (int j = 0; j < 16; ++j)
        row[j] = (p0[j] + p1[j]) + (p2[j] + p3[j]);

    float mx = -3.402823466e38f;
#pragma unroll
    for (int j = 0; j < 16; ++j)
#pragma unroll
        for (int c = 0; c < 4; ++c) mx = fmaxf(mx, row[j][c]);

    float sden = 0.f;
#pragma unroll
    for (int j = 0; j < 16; ++j)
#pragma unroll
        for (int c = 0; c < 4; ++c) sden += expf(row[j][c] - mx);

    float tv[TOPKK];
    int   ti[TOPKK];
#pragma unroll
    for (int i = 0; i < TOPKK; ++i) { tv[i] = -3.402823466e38f; ti[i] = 0; }
#pragma unroll
    for (int j = 0; j < 16; ++j)
#pragma unroll
        for (int c = 0; c < 4; ++c) {
            const float v = row[j][c];
            const int   e = 4 * j + c;
            if (v > tv[TOPKK - 1]) {
                tv[TOPKK - 1] = v; ti[TOPKK - 1] = e;
#pragma unroll
                for (int q = TOPKK - 1; q > 0; --q) {
                    if (tv[q] > tv[q - 1]) {
                        const float fv = tv[q]; tv[q] = tv[q - 1]; tv[q - 1] = fv;
                        const int   iv = ti[q]; ti[q] = ti[q - 1]; ti[q - 1] = iv;
                    }
                }
            }
        }

    float* ow = out + (size_t)g * TOPKK;
    float* oi = out + (size_t)NT * TOPKK + (size_t)g * TOPKK;
#pragma unroll
    for (int i = 0; i < TOPKK; ++i) {
        ow[i] = expf(tv[i] - mx) / sden;   // ROUTE_SCALE == 1.0
        oi[i] = (float)ti[i];
    }
}

// ================= R8 main (fallback if ws < WS_NEED) =================
__device__ __forceinline__ void async16(void* lds, const void* gp) {
    __builtin_amdgcn_global_load_lds(
        (const __attribute__((address_space(1))) unsigned int*)gp,
        (__attribute__((address_space(3))) unsigned int*)lds, 16, 0, 0);
}

__global__ __launch_bounds__(512, 1) void gate_main_r8(
    const float* __restrict__ x, const short* __restrict__ wpk,
    float* __restrict__ out)
{
    __shared__ __align__(16) char smem[8 * 3 * 4096];
    const int tid = threadIdx.x;
    const int w   = tid >> 6;
    const int l   = tid & 63;
    const int r31 = l & 31;
    const int l5  = l >> 5;
    const int tw  = w & 1;
    const int kq  = w >> 1;
    const int bt0 = blockIdx.x * 64;
    char* wbase = smem + w * 12288;
    const int swr = (r31 & 7) ^ (((r31 >> 3) & 3) << 1);
    const int srow = l >> 3;
    const int sg0  = (l & 7) ^ srow;
    const float* xrow0 = x + (size_t)(bt0 + 32 * tw + srow) * DIMK + kq * 512;

#define STAGE_CHUNK(k) do {                                                   \
    _Pragma("unroll")                                                         \
    for (int i = 0; i < 4; ++i) {                                             \
        const float* gsrc = xrow0 + (size_t)(8 * i) * DIMK + (k) * 32         \
                          + ((sg0 ^ (2 * i)) << 2);                           \
        async16(wbase + ((k) % 3) * 4096 + i * 1024, gsrc);                   \
    }                                                                         \
} while (0)

    const short* wq0 = wpk + (size_t)kq * 98304 + l * 8;
    const short* wq1 = wq0 + 1536;
    f32x16 acc0, acc1;
#pragma unroll
    for (int i = 0; i < 16; ++i) { acc0[i] = 0.f; acc1[i] = 0.f; }
    u32x4 w0v[4][3], w1v[4][3];
    STAGE_CHUNK(0); STAGE_CHUNK(1); STAGE_CHUNK(2);
    WLOAD3(w0v[0][0], w0v[0][1], w0v[0][2], wq0); wq0 += 3072;
    WLOAD3(w1v[0][0], w1v[0][1], w1v[0][2], wq1); wq1 += 3072;
    WLOAD3(w0v[1][0], w0v[1][1], w0v[1][2], wq0); wq0 += 3072;
    WLOAD3(w1v[1][0], w1v[1][1], w1v[1][2], wq1); wq1 += 3072;
    WLOAD3(w0v[2][0], w0v[2][1], w0v[2][2], wq0); wq0 += 3072;
    WLOAD3(w1v[2][0], w1v[2][1], w1v[2][2], wq1); wq1 += 3072;

#define SLICE(t) do {                                                         \
    if ((t) <= 28) {                                                          \
        WLOAD3(w0v[((t)+3)&3][0], w0v[((t)+3)&3][1], w0v[((t)+3)&3][2], wq0); \
        wq0 += 3072;                                                          \
        WLOAD3(w1v[((t)+3)&3][0], w1v[((t)+3)&3][1], w1v[((t)+3)&3][2], wq1); \
        wq1 += 3072;                                                          \
    }                                                                         \
    if ((t) <= 1)            WAITN(18);                                       \
    else if ((t) == 29)      WAITN(12);                                       \
    else if ((t) == 30)      WAITN(6);                                        \
    else if ((t) == 31)      WAITN(0);                                        \
    else if (((t) & 1) || (t) == 2 || (t) == 28) WAITN(22);                   \
    else                     WAITN(26);                                       \
    {                                                                         \
        const char* xb = wbase + (((t) >> 1) % 3) * 4096;                     \
        const float4 a0 = *(const float4*)(xb + r31 * 128 +                   \
            (((((t) & 1) * 4 + 2 * l5 + 0) ^ swr) << 4));                     \
        const float4 a1 = *(const float4*)(xb + r31 * 128 +                   \
            (((((t) & 1) * 4 + 2 * l5 + 1) ^ swr) << 4));                     \
        short8 H, M, L;                                                       \
        split3(a0, a1, H, M, L);                                              \
        acc0 = mfma6w(H, M, L, as_s8(w0v[(t)&3][0]), as_s8(w0v[(t)&3][1]),    \
                      as_s8(w0v[(t)&3][2]), acc0);                            \
        acc1 = mfma6w(H, M, L, as_s8(w1v[(t)&3][0]), as_s8(w1v[(t)&3][1]),    \
                      as_s8(w1v[(t)&3][2]), acc1);                            \
    }                                                                         \
    if (((t) & 1) && (t) <= 25) STAGE_CHUNK(((t) + 5) >> 1);                  \
} while (0)

    SLICE(0);  SLICE(1);  SLICE(2);  SLICE(3);
    SLICE(4);  SLICE(5);  SLICE(6);  SLICE(7);
    SLICE(8);  SLICE(9);  SLICE(10); SLICE(11);
    SLICE(12); SLICE(13); SLICE(14); SLICE(15);
    SLICE(16); SLICE(17); SLICE(18); SLICE(19);
    SLICE(20); SLICE(21); SLICE(22); SLICE(23);
    SLICE(24); SLICE(25); SLICE(26); SLICE(27);
    SLICE(28); SLICE(29); SLICE(30); SLICE(31);

    __syncthreads();
    float* lg = (float*)smem;
#pragma unroll
    for (int r = 0; r < 16; ++r) {
        const int rowc = (r & 3) + 8 * (r >> 2) + 4 * l5;
        const int trow = 32 * tw + rowc;
        lg[(kq * 64 + trow) * (NE + 1) + r31]      = acc0[r];
        lg[(kq * 64 + trow) * (NE + 1) + 32 + r31] = acc1[r];
    }
    __syncthreads();
#pragma unroll
    for (int rr = 0; rr < 8; ++rr) {
        const int idx = tid + rr * 512;
        const int t = idx >> 6, e = idx & 63;
        lg[t * (NE + 1) + e] =
            (lg[t * (NE + 1) + e] + lg[(64 + t) * (NE + 1) + e]) +
            (lg[(128 + t) * (NE + 1) + e] + lg[(192 + t) * (NE + 1) + e]);
    }
    __syncthreads();
    if (tid < 64) {
        const float* rowp = lg + tid * (NE + 1);
        float mx = -3.402823466e38f;
        for (int e = 0; e < NE; ++e) mx = fmaxf(mx, rowp[e]);
        float sden = 0.f;
        for (int e = 0; e < NE; ++e) sden += expf(rowp[e] - mx);
        float tv[TOPKK]; int ti[TOPKK];
#pragma unroll
        for (int i = 0; i < TOPKK; ++i) { tv[i] = -3.402823466e38f; ti[i] = 0; }
        for (int e = 0; e < NE; ++e) {
            const float v = rowp[e];
            if (v > tv[TOPKK - 1]) {
                tv[TOPKK - 1] = v; ti[TOPKK - 1] = e;
#pragma unroll
                for (int q = TOPKK - 1; q > 0; --q) {
                    if (tv[q] > tv[q - 1]) {
                        const float fv = tv[q]; tv[q] = tv[q - 1]; tv[q - 1] = fv;
                        const int   iv = ti[q]; ti[q] = ti[q - 1]; ti[q - 1] = iv;
                    }
                }
            }
        }
        float* ow = out + (size_t)(bt0 + tid) * TOPKK;
        float* oi = out + (size_t)NT * TOPKK + (size_t)(bt0 + tid) * TOPKK;
#pragma unroll
        for (int i = 0; i < TOPKK; ++i) {
            ow[i] = expf(tv[i] - mx) / sden;
            oi[i] = (float)ti[i];
        }
    }
#undef SLICE
#undef STAGE_CHUNK
}

extern "C" void kernel_launch(void* const* d_in, const int* in_sizes, int n_in,
                              void* d_out, int out_size, void* d_ws, size_t ws_size,
                              hipStream_t stream) {
    const float* x = (const float*)d_in[0];
    const float* W = (const float*)d_in[1];
    float* out = (float*)d_out;
    short* wpk = (short*)d_ws;
    if (ws_size >= (size_t)WS_NEED) {
        float* pl = (float*)((char*)d_ws + WPK_BYTES);
        hipLaunchKernelGGL(pack_w_kernel, dim3(256), dim3(64), 0, stream, W, wpk);
        hipLaunchKernelGGL(gate_ksplit_kernel, dim3(256), dim3(512), 0, stream,
                           x, wpk, pl);
        hipLaunchKernelGGL(gate_combine_kernel, dim3(NT / 64), dim3(64), 0, stream,
                           pl, out);
    } else if (ws_size >= (size_t)WPK_BYTES) {
        hipLaunchKernelGGL(pack_w_kernel, dim3(256), dim3(64), 0, stream, W, wpk);
        hipLaunchKernelGGL(gate_main_r8, dim3(NT / 64), dim3(512), 0, stream,
                           x, wpk, out);
    }
}

// Round 10
// 59.030 us; speedup vs baseline: 1.0441x; 1.0441x over previous
//
#include <hip/hip_runtime.h>

// MoE gate: logits = x @ W^T (x:[16384,2048] f32, W:[64,2048] f32),
// softmax over 64 experts, top-8 -> weights f32 + indices stored as f32.
//
// R10: R9 K-split structure with three fixes:
//  (1) combine kernel fully coalesced (LDS-staged, 2-way-free banks),
//  (2) x staging aux=0 (drop unverified NT bit),
//  (3) phase-lock barrier every 2 slices -> shared-W L1 window 30KB <= 32KB.
// pack_w -> packed bf16 H/M/L triples (768KB, L2-hot).
// ksplit: grid 256 = 64 tg x 4 kq; 8 waves share one W-quarter stream (L1
// dedupe); wave-private LDS x staging; R8's HW-proven SLICE schedule.
// Traffic: x 128 + W 49 + pl 17+17 = 211MB at the ~6.3 TB/s miss wall.

typedef __attribute__((ext_vector_type(8))) short short8;
typedef __attribute__((ext_vector_type(16))) float f32x16;
typedef __attribute__((ext_vector_type(4))) float f32x4;
typedef __attribute__((ext_vector_type(4))) unsigned int u32x4;

#define NT    16384
#define DIMK  2048
#define NE    64
#define TOPKK 8
#define WPK_BYTES 786432
#define PL_BYTES  (4 * NT * NE * 4)           // 16777216
#define WS_NEED   (WPK_BYTES + PL_BYTES)      // 17563648

union U4S8 { unsigned int u[4]; short8 s; u32x4 v; };

__device__ __forceinline__ short8 as_s8(u32x4 v) { U4S8 t; t.v = v; return t.s; }

// Bit-exact 3-way bf16 split of 8 f32 (truncation; subtractions exact).
__device__ __forceinline__ void split3(const float4 a, const float4 b,
                                       short8& H, short8& M, short8& L) {
    const float f[8] = {a.x, a.y, a.z, a.w, b.x, b.y, b.z, b.w};
    U4S8 uh, um, ul;
#pragma unroll
    for (int p = 0; p < 4; ++p) {
        const float f0 = f[2 * p], f1 = f[2 * p + 1];
        const unsigned int t0 = __float_as_uint(f0) & 0xFFFF0000u;
        const unsigned int t1 = __float_as_uint(f1) & 0xFFFF0000u;
        uh.u[p] = (t0 >> 16) | t1;
        const float r0 = f0 - __uint_as_float(t0);
        const float r1 = f1 - __uint_as_float(t1);
        const unsigned int v0 = __float_as_uint(r0) & 0xFFFF0000u;
        const unsigned int v1 = __float_as_uint(r1) & 0xFFFF0000u;
        um.u[p] = (v0 >> 16) | v1;
        const float s0 = r0 - __uint_as_float(v0);
        const float s1 = r1 - __uint_as_float(v1);
        ul.u[p] = (__float_as_uint(s0) >> 16) | (__float_as_uint(s1) & 0xFFFF0000u);
    }
    H = uh.s; M = um.s; L = ul.s;
}

__device__ __forceinline__ f32x16 mfma6w(short8 ah, short8 am, short8 al,
                                         short8 bh, short8 bm, short8 bl,
                                         f32x16 c) {
    c = __builtin_amdgcn_mfma_f32_32x32x16_bf16(ah, bh, c, 0, 0, 0);
    c = __builtin_amdgcn_mfma_f32_32x32x16_bf16(ah, bm, c, 0, 0, 0);
    c = __builtin_amdgcn_mfma_f32_32x32x16_bf16(am, bh, c, 0, 0, 0);
    c = __builtin_amdgcn_mfma_f32_32x32x16_bf16(ah, bl, c, 0, 0, 0);
    c = __builtin_amdgcn_mfma_f32_32x32x16_bf16(am, bm, c, 0, 0, 0);
    c = __builtin_amdgcn_mfma_f32_32x32x16_bf16(al, bh, c, 0, 0, 0);
    return c;
}

// ---- pack W -> 32x32 B-fragment-ordered bf16 triples (verified R5/R7/R8) --
__global__ __launch_bounds__(64) void pack_w_kernel(
    const float* __restrict__ W, short* __restrict__ wpk)
{
    const int b  = blockIdx.x;          // 256 = c*8 + fg, fg = 2*s16 + n32
    const int c  = b >> 3, fg = b & 7;
    const int s  = fg >> 1, n32 = fg & 1;
    const int l  = threadIdx.x;
    const float* g = W + (size_t)(32 * n32 + (l & 31)) * DIMK
                       + 64 * c + 16 * s + 8 * (l >> 5);
    const float4 lo = *(const float4*)g;
    const float4 hi = *(const float4*)(g + 4);
    short8 H, M, L;
    split3(lo, hi, H, M, L);
    const size_t base = ((size_t)(c * 8 + fg) * 3) * 512 + l * 8;
    *(short8*)(wpk + base)        = H;
    *(short8*)(wpk + base + 512)  = M;
    *(short8*)(wpk + base + 1024) = L;
}

#define WLOAD3(d0, d1, d2, p)                                                 \
    asm volatile("global_load_dwordx4 %0, %3, off\n\t"                        \
                 "global_load_dwordx4 %1, %3, off offset:1024\n\t"            \
                 "global_load_dwordx4 %2, %3, off offset:2048"                \
                 : "=&v"(d0), "=&v"(d1), "=&v"(d2) : "v"(p))
#define WAITN(n) do {                                                         \
    asm volatile("s_waitcnt vmcnt(" #n ")" ::: "memory");                     \
    __builtin_amdgcn_sched_barrier(0);                                        \
} while (0)

__device__ __forceinline__ void async16(void* lds, const void* gp) {
    __builtin_amdgcn_global_load_lds(
        (const __attribute__((address_space(1))) unsigned int*)gp,
        (__attribute__((address_space(3))) unsigned int*)lds, 16, 0, 0);
}

// ================= R10 main: K-split, shared W stream =================
__global__ __launch_bounds__(512, 1) void gate_ksplit_kernel(
    const float* __restrict__ x, const short* __restrict__ wpk,
    float* __restrict__ pl)
{
    __shared__ __align__(16) char smem[8 * 3 * 4096];   // wave-private staging

    const int tid = threadIdx.x;
    const int w   = tid >> 6;
    const int l   = tid & 63;
    const int r31 = l & 31;
    const int l5  = l >> 5;
    const int tg  = blockIdx.x >> 2;     // token group (256 tokens)
    const int kq  = blockIdx.x & 3;      // K quarter
    const int bt0 = tg * 256;
    const int tokbase = bt0 + 32 * w;    // wave's 32 tokens

    char* wbase = smem + w * 12288;
    const int swr = (r31 & 7) ^ (((r31 >> 3) & 3) << 1);
    const int srow = l >> 3;
    const int sg0  = (l & 7) ^ srow;
    const float* xrow0 = x + (size_t)(tokbase + srow) * DIMK + kq * 512;

#define STAGE_CHUNK(k) do {                                                   \
    _Pragma("unroll")                                                         \
    for (int i = 0; i < 4; ++i) {                                             \
        const float* gsrc = xrow0 + (size_t)(8 * i) * DIMK + (k) * 32         \
                          + ((sg0 ^ (2 * i)) << 2);                           \
        async16(wbase + ((k) % 3) * 4096 + i * 1024, gsrc);                   \
    }                                                                         \
} while (0)

    // ALL 8 waves share this stream (L1 dedupe is the point)
    const short* wq0 = wpk + (size_t)kq * 98304 + l * 8;
    const short* wq1 = wq0 + 1536;

    f32x16 acc0, acc1;
#pragma unroll
    for (int i = 0; i < 16; ++i) { acc0[i] = 0.f; acc1[i] = 0.f; }

    u32x4 w0v[4][3], w1v[4][3];

    STAGE_CHUNK(0);
    STAGE_CHUNK(1);
    STAGE_CHUNK(2);
    WLOAD3(w0v[0][0], w0v[0][1], w0v[0][2], wq0); wq0 += 3072;
    WLOAD3(w1v[0][0], w1v[0][1], w1v[0][2], wq1); wq1 += 3072;
    WLOAD3(w0v[1][0], w0v[1][1], w0v[1][2], wq0); wq0 += 3072;
    WLOAD3(w1v[1][0], w1v[1][1], w1v[1][2], wq1); wq1 += 3072;
    WLOAD3(w0v[2][0], w0v[2][1], w0v[2][2], wq0); wq0 += 3072;
    WLOAD3(w1v[2][0], w1v[2][1], w1v[2][2], wq1); wq1 += 3072;

    // R8's HW-proven schedule, verbatim literals.
#define SLICE(t) do {                                                         \
    if ((t) <= 28) {                                                          \
        WLOAD3(w0v[((t)+3)&3][0], w0v[((t)+3)&3][1], w0v[((t)+3)&3][2], wq0); \
        wq0 += 3072;                                                          \
        WLOAD3(w1v[((t)+3)&3][0], w1v[((t)+3)&3][1], w1v[((t)+3)&3][2], wq1); \
        wq1 += 3072;                                                          \
    }                                                                         \
    if ((t) <= 1)            WAITN(18);                                       \
    else if ((t) == 29)      WAITN(12);                                       \
    else if ((t) == 30)      WAITN(6);                                        \
    else if ((t) == 31)      WAITN(0);                                        \
    else if (((t) & 1) || (t) == 2 || (t) == 28) WAITN(22);                   \
    else                     WAITN(26);                                       \
    {                                                                         \
        const char* xb = wbase + (((t) >> 1) % 3) * 4096;                     \
        const float4 a0 = *(const float4*)(xb + r31 * 128 +                   \
            (((((t) & 1) * 4 + 2 * l5 + 0) ^ swr) << 4));                     \
        const float4 a1 = *(const float4*)(xb + r31 * 128 +                   \
            (((((t) & 1) * 4 + 2 * l5 + 1) ^ swr) << 4));                     \
        short8 H, M, L;                                                       \
        split3(a0, a1, H, M, L);                                              \
        acc0 = mfma6w(H, M, L, as_s8(w0v[(t)&3][0]), as_s8(w0v[(t)&3][1]),    \
                      as_s8(w0v[(t)&3][2]), acc0);                            \
        acc1 = mfma6w(H, M, L, as_s8(w1v[(t)&3][0]), as_s8(w1v[(t)&3][1]),    \
                      as_s8(w1v[(t)&3][2]), acc1);                            \
    }                                                                         \
    if (((t) & 1) && (t) <= 25) STAGE_CHUNK(((t) + 5) >> 1);                  \
} while (0)

#define PBAR() __builtin_amdgcn_s_barrier()   // phase-lock only (no LDS dep)

    SLICE(0);  SLICE(1);  PBAR();
    SLICE(2);  SLICE(3);  PBAR();
    SLICE(4);  SLICE(5);  PBAR();
    SLICE(6);  SLICE(7);  PBAR();
    SLICE(8);  SLICE(9);  PBAR();
    SLICE(10); SLICE(11); PBAR();
    SLICE(12); SLICE(13); PBAR();
    SLICE(14); SLICE(15); PBAR();
    SLICE(16); SLICE(17); PBAR();
    SLICE(18); SLICE(19); PBAR();
    SLICE(20); SLICE(21); PBAR();
    SLICE(22); SLICE(23); PBAR();
    SLICE(24); SLICE(25); PBAR();
    SLICE(26); SLICE(27); PBAR();
    SLICE(28); SLICE(29); PBAR();
    SLICE(30); SLICE(31);

    // partial logits -> pl[kq][NT][64]; C/D: col=l&31, row=(r&3)+8*(r>>2)+4*l5
    float* base0 = pl + ((size_t)kq * NT + tokbase) * NE;
#pragma unroll
    for (int r = 0; r < 16; ++r) {
        const int rowc = (r & 3) + 8 * (r >> 2) + 4 * l5;
        base0[rowc * NE + r31]      = acc0[r];
        base0[rowc * NE + 32 + r31] = acc1[r];
    }
#undef SLICE
#undef STAGE_CHUNK
#undef PBAR
}

// ========== combine: coalesced LDS-staged sum + softmax + top-8 ==========
__global__ __launch_bounds__(128) void gate_combine_kernel(
    const float* __restrict__ pl, float* __restrict__ out)
{
    __shared__ float lgs[128][NE + 1];    // 33.3 KB; 2-way banks (free)

    const int tid = threadIdx.x;
    const int t0  = blockIdx.x * 128;

    // Stage: 128 tokens x 16 f32x4 per kq plane; consecutive lanes read
    // consecutive 16B (fully coalesced). Sum order (p0+p1)+(p2+p3) == R9.
#pragma unroll
    for (int i = 0; i < 16; ++i) {
        const int idx = i * 128 + tid;          // 0..2047
        const int tok = idx >> 4, c4 = idx & 15;
        const size_t off = ((size_t)t0 + tok) * NE + c4 * 4;
        const f32x4 v0 = *(const f32x4*)(pl + off);
        const f32x4 v1 = *(const f32x4*)(pl + (size_t)NT * NE + off);
        const f32x4 v2 = *(const f32x4*)(pl + (size_t)2 * NT * NE + off);
        const f32x4 v3 = *(const f32x4*)(pl + (size_t)3 * NT * NE + off);
        const f32x4 s = (v0 + v1) + (v2 + v3);
#pragma unroll
        for (int j = 0; j < 4; ++j) lgs[tok][c4 * 4 + j] = s[j];
    }
    __syncthreads();

    const float* rowp = &lgs[tid][0];
    float mx = -3.402823466e38f;
    for (int e = 0; e < NE; ++e) mx = fmaxf(mx, rowp[e]);
    float sden = 0.f;
    for (int e = 0; e < NE; ++e) sden += expf(rowp[e] - mx);

    float tv[TOPKK];
    int   ti[TOPKK];
#pragma unroll
    for (int i = 0; i < TOPKK; ++i) { tv[i] = -3.402823466e38f; ti[i] = 0; }
    for (int e = 0; e < NE; ++e) {
        const float v = rowp[e];
        if (v > tv[TOPKK - 1]) {
            tv[TOPKK - 1] = v; ti[TOPKK - 1] = e;
#pragma unroll
            for (int q = TOPKK - 1; q > 0; --q) {
                if (tv[q] > tv[q - 1]) {
                    const float fv = tv[q]; tv[q] = tv[q - 1]; tv[q - 1] = fv;
                    const int   iv = ti[q]; ti[q] = ti[q - 1]; ti[q - 1] = iv;
                }
            }
        }
    }

    float* ow = out + (size_t)(t0 + tid) * TOPKK;
    float* oi = out + (size_t)NT * TOPKK + (size_t)(t0 + tid) * TOPKK;
#pragma unroll
    for (int i = 0; i < TOPKK; ++i) {
        ow[i] = expf(tv[i] - mx) / sden;   // ROUTE_SCALE == 1.0
        oi[i] = (float)ti[i];
    }
}

// ================= R8 main (fallback if ws < WS_NEED) =================
__global__ __launch_bounds__(512, 1) void gate_main_r8(
    const float* __restrict__ x, const short* __restrict__ wpk,
    float* __restrict__ out)
{
    __shared__ __align__(16) char smem[8 * 3 * 4096];
    const int tid = threadIdx.x;
    const int w   = tid >> 6;
    const int l   = tid & 63;
    const int r31 = l & 31;
    const int l5  = l >> 5;
    const int tw  = w & 1;
    const int kq  = w >> 1;
    const int bt0 = blockIdx.x * 64;
    char* wbase = smem + w * 12288;
    const int swr = (r31 & 7) ^ (((r31 >> 3) & 3) << 1);
    const int srow = l >> 3;
    const int sg0  = (l & 7) ^ srow;
    const float* xrow0 = x + (size_t)(bt0 + 32 * tw + srow) * DIMK + kq * 512;

#define STAGE_CHUNK(k) do {                                                   \
    _Pragma("unroll")                                                         \
    for (int i = 0; i < 4; ++i) {                                             \
        const float* gsrc = xrow0 + (size_t)(8 * i) * DIMK + (k) * 32         \
                          + ((sg0 ^ (2 * i)) << 2);                           \
        async16(wbase + ((k) % 3) * 4096 + i * 1024, gsrc);                   \
    }                                                                         \
} while (0)

    const short* wq0 = wpk + (size_t)kq * 98304 + l * 8;
    const short* wq1 = wq0 + 1536;
    f32x16 acc0, acc1;
#pragma unroll
    for (int i = 0; i < 16; ++i) { acc0[i] = 0.f; acc1[i] = 0.f; }
    u32x4 w0v[4][3], w1v[4][3];
    STAGE_CHUNK(0); STAGE_CHUNK(1); STAGE_CHUNK(2);
    WLOAD3(w0v[0][0], w0v[0][1], w0v[0][2], wq0); wq0 += 3072;
    WLOAD3(w1v[0][0], w1v[0][1], w1v[0][2], wq1); wq1 += 3072;
    WLOAD3(w0v[1][0], w0v[1][1], w0v[1][2], wq0); wq0 += 3072;
    WLOAD3(w1v[1][0], w1v[1][1], w1v[1][2], wq1); wq1 += 3072;
    WLOAD3(w0v[2][0], w0v[2][1], w0v[2][2], wq0); wq0 += 3072;
    WLOAD3(w1v[2][0], w1v[2][1], w1v[2][2], wq1); wq1 += 3072;

#define SLICE(t) do {                                                         \
    if ((t) <= 28) {                                                          \
        WLOAD3(w0v[((t)+3)&3][0], w0v[((t)+3)&3][1], w0v[((t)+3)&3][2], wq0); \
        wq0 += 3072;                                                          \
        WLOAD3(w1v[((t)+3)&3][0], w1v[((t)+3)&3][1], w1v[((t)+3)&3][2], wq1); \
        wq1 += 3072;                                                          \
    }                                                                         \
    if ((t) <= 1)            WAITN(18);                                       \
    else if ((t) == 29)      WAITN(12);                                       \
    else if ((t) == 30)      WAITN(6);                                        \
    else if ((t) == 31)      WAITN(0);                                        \
    else if (((t) & 1) || (t) == 2 || (t) == 28) WAITN(22);                   \
    else                     WAITN(26);                                       \
    {                                                                         \
        const char* xb = wbase + (((t) >> 1) % 3) * 4096;                     \
        const float4 a0 = *(const float4*)(xb + r31 * 128 +                   \
            (((((t) & 1) * 4 + 2 * l5 + 0) ^ swr) << 4));                     \
        const float4 a1 = *(const float4*)(xb + r31 * 128 +                   \
            (((((t) & 1) * 4 + 2 * l5 + 1) ^ swr) << 4));                     \
        short8 H, M, L;                                                       \
        split3(a0, a1, H, M, L);                                              \
        acc0 = mfma6w(H, M, L, as_s8(w0v[(t)&3][0]), as_s8(w0v[(t)&3][1]),    \
                      as_s8(w0v[(t)&3][2]), acc0);                            \
        acc1 = mfma6w(H, M, L, as_s8(w1v[(t)&3][0]), as_s8(w1v[(t)&3][1]),    \
                      as_s8(w1v[(t)&3][2]), acc1);                            \
    }                                                                         \
    if (((t) & 1) && (t) <= 25) STAGE_CHUNK(((t) + 5) >> 1);                  \
} while (0)

    SLICE(0);  SLICE(1);  SLICE(2);  SLICE(3);
    SLICE(4);  SLICE(5);  SLICE(6);  SLICE(7);
    SLICE(8);  SLICE(9);  SLICE(10); SLICE(11);
    SLICE(12); SLICE(13); SLICE(14); SLICE(15);
    SLICE(16); SLICE(17); SLICE(18); SLICE(19);
    SLICE(20); SLICE(21); SLICE(22); SLICE(23);
    SLICE(24); SLICE(25); SLICE(26); SLICE(27);
    SLICE(28); SLICE(29); SLICE(30); SLICE(31);

    __syncthreads();
    float* lg = (float*)smem;
#pragma unroll
    for (int r = 0; r < 16; ++r) {
        const int rowc = (r & 3) + 8 * (r >> 2) + 4 * l5;
        const int trow = 32 * tw + rowc;
        lg[(kq * 64 + trow) * (NE + 1) + r31]      = acc0[r];
        lg[(kq * 64 + trow) * (NE + 1) + 32 + r31] = acc1[r];
    }
    __syncthreads();
#pragma unroll
    for (int rr = 0; rr < 8; ++rr) {
        const int idx = tid + rr * 512;
        const int t = idx >> 6, e = idx & 63;
        lg[t * (NE + 1) + e] =
            (lg[t * (NE + 1) + e] + lg[(64 + t) * (NE + 1) + e]) +
            (lg[(128 + t) * (NE + 1) + e] + lg[(192 + t) * (NE + 1) + e]);
    }
    __syncthreads();
    if (tid < 64) {
        const float* rowp = lg + tid * (NE + 1);
        float mx = -3.402823466e38f;
        for (int e = 0; e < NE; ++e) mx = fmaxf(mx, rowp[e]);
        float sden = 0.f;
        for (int e = 0; e < NE; ++e) sden += expf(rowp[e] - mx);
        float tv[TOPKK]; int ti[TOPKK];
#pragma unroll
        for (int i = 0; i < TOPKK; ++i) { tv[i] = -3.402823466e38f; ti[i] = 0; }
        for (int e = 0; e < NE; ++e) {
            const float v = rowp[e];
            if (v > tv[TOPKK - 1]) {
                tv[TOPKK - 1] = v; ti[TOPKK - 1] = e;
#pragma unroll
                for (int q = TOPKK - 1; q > 0; --q) {
                    if (tv[q] > tv[q - 1]) {
                        const float fv = tv[q]; tv[q] = tv[q - 1]; tv[q - 1] = fv;
                        const int   iv = ti[q]; ti[q] = ti[q - 1]; ti[q - 1] = iv;
                    }
                }
            }
        }
        float* ow = out + (size_t)(bt0 + tid) * TOPKK;
        float* oi = out + (size_t)NT * TOPKK + (size_t)(bt0 + tid) * TOPKK;
#pragma unroll
        for (int i = 0; i < TOPKK; ++i) {
            ow[i] = expf(tv[i] - mx) / sden;
            oi[i] = (float)ti[i];
        }
    }
#undef SLICE
#undef STAGE_CHUNK
}

extern "C" void kernel_launch(void* const* d_in, const int* in_sizes, int n_in,
                              void* d_out, int out_size, void* d_ws, size_t ws_size,
                              hipStream_t stream) {
    const float* x = (const float*)d_in[0];
    const float* W = (const float*)d_in[1];
    float* out = (float*)d_out;
    short* wpk = (short*)d_ws;
    if (ws_size >= (size_t)WS_NEED) {
        float* pl = (float*)((char*)d_ws + WPK_BYTES);
        hipLaunchKernelGGL(pack_w_kernel, dim3(256), dim3(64), 0, stream, W, wpk);
        hipLaunchKernelGGL(gate_ksplit_kernel, dim3(256), dim3(512), 0, stream,
                           x, wpk, pl);
        hipLaunchKernelGGL(gate_combine_kernel, dim3(NT / 128), dim3(128), 0, stream,
                           pl, out);
    } else if (ws_size >= (size_t)WPK_BYTES) {
        hipLaunchKernelGGL(pack_w_kernel, dim3(256), dim3(64), 0, stream, W, wpk);
        hipLaunchKernelGGL(gate_main_r8, dim3(NT / 64), dim3(512), 0, stream,
                           x, wpk, out);
    }
}

// Round 11
// 57.109 us; speedup vs baseline: 1.0792x; 1.0336x over previous
//
#include <hip/hip_runtime.h>

// MoE gate: logits = x @ W^T (x:[16384,2048] f32, W:[64,2048] f32),
// softmax over 64 experts, top-8 -> weights f32 + indices stored as f32.
//
// R11: K-split with GUARANTEED W dedupe via LDS staging.
//  pack_w:  W -> packed bf16 H/M/L fragment triples (768KB, L2-hot).
//  ksplit2: grid 256 = 64 tg(256 tok) x 4 kq(512 K); per 32-K chunk the
//           12KB W slice is staged ONCE per block into a 4-deep LDS ring
//           (waves 0-5, contiguous 1KB instrs); all 8 waves ds_read it.
//           x = R8's proven wave-private 3-deep LDS staging (issued after
//           compute, WAR-safe). 1 s_barrier/chunk; per-wave counted vmcnt
//           (FIFO-audited literals, group A=stagers / B=non-stagers).
//  combine: coalesced LDS-staged 4-way sum + fused softmax/top-8 (R10).
// Traffic: x 128 + W 49 + pl 34 = 211MB (vs R8 324MB).

typedef __attribute__((ext_vector_type(8))) short short8;
typedef __attribute__((ext_vector_type(16))) float f32x16;
typedef __attribute__((ext_vector_type(4))) float f32x4;
typedef __attribute__((ext_vector_type(4))) unsigned int u32x4;

#define NT    16384
#define DIMK  2048
#define NE    64
#define TOPKK 8
#define WPK_BYTES 786432
#define PL_BYTES  (4 * NT * NE * 4)           // 16777216
#define WS_NEED   (WPK_BYTES + PL_BYTES)
#define KS2_LDS   (4 * 12288 + 8 * 12288)     // 147456

union U4S8 { unsigned int u[4]; short8 s; u32x4 v; };

__device__ __forceinline__ short8 as_s8(u32x4 v) { U4S8 t; t.v = v; return t.s; }

// Bit-exact 3-way bf16 split of 8 f32 (truncation; subtractions exact).
__device__ __forceinline__ void split3(const float4 a, const float4 b,
                                       short8& H, short8& M, short8& L) {
    const float f[8] = {a.x, a.y, a.z, a.w, b.x, b.y, b.z, b.w};
    U4S8 uh, um, ul;
#pragma unroll
    for (int p = 0; p < 4; ++p) {
        const float f0 = f[2 * p], f1 = f[2 * p + 1];
        const unsigned int t0 = __float_as_uint(f0) & 0xFFFF0000u;
        const unsigned int t1 = __float_as_uint(f1) & 0xFFFF0000u;
        uh.u[p] = (t0 >> 16) | t1;
        const float r0 = f0 - __uint_as_float(t0);
        const float r1 = f1 - __uint_as_float(t1);
        const unsigned int v0 = __float_as_uint(r0) & 0xFFFF0000u;
        const unsigned int v1 = __float_as_uint(r1) & 0xFFFF0000u;
        um.u[p] = (v0 >> 16) | v1;
        const float s0 = r0 - __uint_as_float(v0);
        const float s1 = r1 - __uint_as_float(v1);
        ul.u[p] = (__float_as_uint(s0) >> 16) | (__float_as_uint(s1) & 0xFFFF0000u);
    }
    H = uh.s; M = um.s; L = ul.s;
}

__device__ __forceinline__ f32x16 mfma6w(short8 ah, short8 am, short8 al,
                                         short8 bh, short8 bm, short8 bl,
                                         f32x16 c) {
    c = __builtin_amdgcn_mfma_f32_32x32x16_bf16(ah, bh, c, 0, 0, 0);
    c = __builtin_amdgcn_mfma_f32_32x32x16_bf16(ah, bm, c, 0, 0, 0);
    c = __builtin_amdgcn_mfma_f32_32x32x16_bf16(am, bh, c, 0, 0, 0);
    c = __builtin_amdgcn_mfma_f32_32x32x16_bf16(ah, bl, c, 0, 0, 0);
    c = __builtin_amdgcn_mfma_f32_32x32x16_bf16(am, bm, c, 0, 0, 0);
    c = __builtin_amdgcn_mfma_f32_32x32x16_bf16(al, bh, c, 0, 0, 0);
    return c;
}

// ---- pack W -> 32x32 B-fragment bf16 triples (HW-verified R5/R7/R8) ----
// layout: base shorts = ((c64*8 + fg)*3 + t)*512 + lane*8; fg = 2*s16+n32.
__global__ __launch_bounds__(64) void pack_w_kernel(
    const float* __restrict__ W, short* __restrict__ wpk)
{
    const int b  = blockIdx.x;
    const int c  = b >> 3, fg = b & 7;
    const int s  = fg >> 1, n32 = fg & 1;
    const int l  = threadIdx.x;
    const float* g = W + (size_t)(32 * n32 + (l & 31)) * DIMK
                       + 64 * c + 16 * s + 8 * (l >> 5);
    const float4 lo = *(const float4*)g;
    const float4 hi = *(const float4*)(g + 4);
    short8 H, M, L;
    split3(lo, hi, H, M, L);
    const size_t base = ((size_t)(c * 8 + fg) * 3) * 512 + l * 8;
    *(short8*)(wpk + base)        = H;
    *(short8*)(wpk + base + 512)  = M;
    *(short8*)(wpk + base + 1024) = L;
}

#define WAITN(n) do {                                                         \
    asm volatile("s_waitcnt vmcnt(" #n ")" ::: "memory");                     \
    __builtin_amdgcn_sched_barrier(0);                                        \
} while (0)
#define BAR() do {                                                            \
    __builtin_amdgcn_sched_barrier(0);                                        \
    __builtin_amdgcn_s_barrier();                                             \
    __builtin_amdgcn_sched_barrier(0);                                        \
} while (0)

__device__ __forceinline__ void async16(void* lds, const void* gp) {
    __builtin_amdgcn_global_load_lds(
        (const __attribute__((address_space(1))) unsigned int*)gp,
        (__attribute__((address_space(3))) unsigned int*)lds, 16, 0, 0);
}

// ================= R11 main: K-split, W via shared LDS ring =================
__global__ __launch_bounds__(512, 1) void gate_ksplit2_kernel(
    const float* __restrict__ x, const short* __restrict__ wpk,
    float* __restrict__ pl)
{
    extern __shared__ __align__(16) char smem[];
    // [0, 49152): W ring, 4 bufs x 12KB (chunk = 2 slices x {n32 x t} x 1KB)
    // [49152, 147456): x staging, 8 waves x 3 bufs x 4KB (wave-private)

    const int tid = threadIdx.x;
    const int w   = tid >> 6;
    const int l   = tid & 63;
    const int r31 = l & 31;
    const int l5  = l >> 5;
    const int tg  = blockIdx.x >> 2;     // token group (256 tokens)
    const int kq  = blockIdx.x & 3;      // K quarter (512 K = 16 chunks of 32)
    const int tokbase = tg * 256 + 32 * w;

    char* xbase = smem + 49152 + w * 12288;
    const int swr = (r31 & 7) ^ (((r31 >> 3) & 3) << 1);
    const int srow = l >> 3;
    const int sg0  = (l & 7) ^ srow;
    const float* xrow0 = x + (size_t)(tokbase + srow) * DIMK + kq * 512;

    // x staging: R8's proven pattern (4 x 1KB, 128B runs, granule-XOR src)
#define KS2_STAGE_X(k) do {                                                   \
    _Pragma("unroll")                                                         \
    for (int i = 0; i < 4; ++i) {                                             \
        const float* gsrc = xrow0 + (size_t)(8 * i) * DIMK + (k) * 32         \
                          + ((sg0 ^ (2 * i)) << 2);                           \
        async16(xbase + ((k) % 3) * 4096 + i * 1024, gsrc);                   \
    }                                                                         \
} while (0)

    // W staging: waves 0-5 stage regions {2w, 2w+1} of chunk cc (2KB/wave).
    // region r: ss=r>=6, n32=(r%6)>=3, t=r%3; fg = 2*(2*(cc&1)+ss)+n32.
#define KS2_STAGE_W(cc) do {                                                  \
    if (w < 6) {                                                              \
        _Pragma("unroll")                                                     \
        for (int rr = 0; rr < 2; ++rr) {                                      \
            const int r   = 2 * w + rr;                                       \
            const int ss  = (r >= 6) ? 1 : 0;                                 \
            const int rm  = r - 6 * ss;                                       \
            const int n32 = (rm >= 3) ? 1 : 0;                                \
            const int t   = rm - 3 * n32;                                     \
            const int fg  = 2 * (2 * ((cc) & 1) + ss) + n32;                  \
            const int c64g = kq * 8 + ((cc) >> 1);                            \
            const short* gs = wpk + ((size_t)(c64g * 8 + fg) * 3 + t) * 512   \
                            + l * 8;                                          \
            async16(smem + ((cc) & 3) * 12288 + r * 1024, gs);                \
        }                                                                     \
    }                                                                         \
} while (0)

#define KS2_COMPUTE(cc) do {                                                  \
    const char* xb = xbase + ((cc) % 3) * 4096;                               \
    const char* wb = smem + ((cc) & 3) * 12288;                               \
    _Pragma("unroll")                                                         \
    for (int ss = 0; ss < 2; ++ss) {                                          \
        const float4 a0 = *(const float4*)(xb + r31 * 128 +                   \
            (((4 * ss + 2 * l5 + 0) ^ swr) << 4));                            \
        const float4 a1 = *(const float4*)(xb + r31 * 128 +                   \
            (((4 * ss + 2 * l5 + 1) ^ swr) << 4));                            \
        short8 H, M, L;                                                       \
        split3(a0, a1, H, M, L);                                              \
        const char* wsl = wb + ss * 6144 + l * 16;                            \
        const short8 b00 = *(const short8*)(wsl);                             \
        const short8 b01 = *(const short8*)(wsl + 1024);                      \
        const short8 b02 = *(const short8*)(wsl + 2048);                      \
        const short8 b10 = *(const short8*)(wsl + 3072);                      \
        const short8 b11 = *(const short8*)(wsl + 4096);                      \
        const short8 b12 = *(const short8*)(wsl + 5120);                      \
        acc0 = mfma6w(H, M, L, b00, b01, b02, acc0);                          \
        acc1 = mfma6w(H, M, L, b10, b11, b12, acc1);                          \
    }                                                                         \
} while (0)

    // iter c: [stage W(c+2)] [counted waits] [BAR] [compute c] [stage x(c+3)]
    // FIFO-audited literals: steady (c<=13) A=12 / B=8; c=14: 6/4; c=15: 0.
#define KS2_ITER(c) do {                                                      \
    if ((c) <= 13) KS2_STAGE_W((c) + 2);                                      \
    if ((c) <= 13)      { if (w < 6) WAITN(12); else WAITN(8); }              \
    else if ((c) == 14) { if (w < 6) WAITN(6);  else WAITN(4); }              \
    else                { WAITN(0); }                                         \
    BAR();                                                                    \
    KS2_COMPUTE(c);                                                           \
    if ((c) <= 12) KS2_STAGE_X((c) + 3);                                      \
} while (0)

    f32x16 acc0, acc1;
#pragma unroll
    for (int i = 0; i < 16; ++i) { acc0[i] = 0.f; acc1[i] = 0.f; }

    // prologue: order x0, W0, x1, W1, x2 reproduces the steady FIFO
    KS2_STAGE_X(0);
    KS2_STAGE_W(0);
    KS2_STAGE_X(1);
    KS2_STAGE_W(1);
    KS2_STAGE_X(2);

    KS2_ITER(0);  KS2_ITER(1);  KS2_ITER(2);  KS2_ITER(3);
    KS2_ITER(4);  KS2_ITER(5);  KS2_ITER(6);  KS2_ITER(7);
    KS2_ITER(8);  KS2_ITER(9);  KS2_ITER(10); KS2_ITER(11);
    KS2_ITER(12); KS2_ITER(13); KS2_ITER(14); KS2_ITER(15);

    // partial logits -> pl[kq][NT][64]; C/D: col=l&31, row=(r&3)+8*(r>>2)+4*l5
    float* base0 = pl + ((size_t)kq * NT + tokbase) * NE;
#pragma unroll
    for (int r = 0; r < 16; ++r) {
        const int rowc = (r & 3) + 8 * (r >> 2) + 4 * l5;
        base0[rowc * NE + r31]      = acc0[r];
        base0[rowc * NE + 32 + r31] = acc1[r];
    }
#undef KS2_ITER
#undef KS2_COMPUTE
#undef KS2_STAGE_W
#undef KS2_STAGE_X
}

// ========== combine: coalesced LDS-staged sum + softmax + top-8 ==========
__global__ __launch_bounds__(128) void gate_combine_kernel(
    const float* __restrict__ pl, float* __restrict__ out)
{
    __shared__ float lgs[128][NE + 1];

    const int tid = threadIdx.x;
    const int t0  = blockIdx.x * 128;

#pragma unroll
    for (int i = 0; i < 16; ++i) {
        const int idx = i * 128 + tid;
        const int tok = idx >> 4, c4 = idx & 15;
        const size_t off = ((size_t)t0 + tok) * NE + c4 * 4;
        const f32x4 v0 = *(const f32x4*)(pl + off);
        const f32x4 v1 = *(const f32x4*)(pl + (size_t)NT * NE + off);
        const f32x4 v2 = *(const f32x4*)(pl + (size_t)2 * NT * NE + off);
        const f32x4 v3 = *(const f32x4*)(pl + (size_t)3 * NT * NE + off);
        const f32x4 s = (v0 + v1) + (v2 + v3);
#pragma unroll
        for (int j = 0; j < 4; ++j) lgs[tok][c4 * 4 + j] = s[j];
    }
    __syncthreads();

    const float* rowp = &lgs[tid][0];
    float mx = -3.402823466e38f;
    for (int e = 0; e < NE; ++e) mx = fmaxf(mx, rowp[e]);
    float sden = 0.f;
    for (int e = 0; e < NE; ++e) sden += expf(rowp[e] - mx);

    float tv[TOPKK];
    int   ti[TOPKK];
#pragma unroll
    for (int i = 0; i < TOPKK; ++i) { tv[i] = -3.402823466e38f; ti[i] = 0; }
    for (int e = 0; e < NE; ++e) {
        const float v = rowp[e];
        if (v > tv[TOPKK - 1]) {
            tv[TOPKK - 1] = v; ti[TOPKK - 1] = e;
#pragma unroll
            for (int q = TOPKK - 1; q > 0; --q) {
                if (tv[q] > tv[q - 1]) {
                    const float fv = tv[q]; tv[q] = tv[q - 1]; tv[q - 1] = fv;
                    const int   iv = ti[q]; ti[q] = ti[q - 1]; ti[q - 1] = iv;
                }
            }
        }
    }

    float* ow = out + (size_t)(t0 + tid) * TOPKK;
    float* oi = out + (size_t)NT * TOPKK + (size_t)(t0 + tid) * TOPKK;
#pragma unroll
    for (int i = 0; i < TOPKK; ++i) {
        ow[i] = expf(tv[i] - mx) / sden;   // ROUTE_SCALE == 1.0
        oi[i] = (float)ti[i];
    }
}

// ================= R8 main (fallback if ws < WS_NEED) =================
#define WLOAD3(d0, d1, d2, p)                                                 \
    asm volatile("global_load_dwordx4 %0, %3, off\n\t"                        \
                 "global_load_dwordx4 %1, %3, off offset:1024\n\t"            \
                 "global_load_dwordx4 %2, %3, off offset:2048"                \
                 : "=&v"(d0), "=&v"(d1), "=&v"(d2) : "v"(p))

__global__ __launch_bounds__(512, 1) void gate_main_r8(
    const float* __restrict__ x, const short* __restrict__ wpk,
    float* __restrict__ out)
{
    __shared__ __align__(16) char smem8[8 * 3 * 4096];
    const int tid = threadIdx.x;
    const int w   = tid >> 6;
    const int l   = tid & 63;
    const int r31 = l & 31;
    const int l5  = l >> 5;
    const int tw  = w & 1;
    const int kq  = w >> 1;
    const int bt0 = blockIdx.x * 64;
    char* wbase = smem8 + w * 12288;
    const int swr = (r31 & 7) ^ (((r31 >> 3) & 3) << 1);
    const int srow = l >> 3;
    const int sg0  = (l & 7) ^ srow;
    const float* xrow0 = x + (size_t)(bt0 + 32 * tw + srow) * DIMK + kq * 512;

#define STAGE_CHUNK(k) do {                                                   \
    _Pragma("unroll")                                                         \
    for (int i = 0; i < 4; ++i) {                                             \
        const float* gsrc = xrow0 + (size_t)(8 * i) * DIMK + (k) * 32         \
                          + ((sg0 ^ (2 * i)) << 2);                           \
        async16(wbase + ((k) % 3) * 4096 + i * 1024, gsrc);                   \
    }                                                                         \
} while (0)

    const short* wq0 = wpk + (size_t)kq * 98304 + l * 8;
    const short* wq1 = wq0 + 1536;
    f32x16 acc0, acc1;
#pragma unroll
    for (int i = 0; i < 16; ++i) { acc0[i] = 0.f; acc1[i] = 0.f; }
    u32x4 w0v[4][3], w1v[4][3];
    STAGE_CHUNK(0); STAGE_CHUNK(1); STAGE_CHUNK(2);
    WLOAD3(w0v[0][0], w0v[0][1], w0v[0][2], wq0); wq0 += 3072;
    WLOAD3(w1v[0][0], w1v[0][1], w1v[0][2], wq1); wq1 += 3072;
    WLOAD3(w0v[1][0], w0v[1][1], w0v[1][2], wq0); wq0 += 3072;
    WLOAD3(w1v[1][0], w1v[1][1], w1v[1][2], wq1); wq1 += 3072;
    WLOAD3(w0v[2][0], w0v[2][1], w0v[2][2], wq0); wq0 += 3072;
    WLOAD3(w1v[2][0], w1v[2][1], w1v[2][2], wq1); wq1 += 3072;

#define SLICE(t) do {                                                         \
    if ((t) <= 28) {                                                          \
        WLOAD3(w0v[((t)+3)&3][0], w0v[((t)+3)&3][1], w0v[((t)+3)&3][2], wq0); \
        wq0 += 3072;                                                          \
        WLOAD3(w1v[((t)+3)&3][0], w1v[((t)+3)&3][1], w1v[((t)+3)&3][2], wq1); \
        wq1 += 3072;                                                          \
    }                                                                         \
    if ((t) <= 1)            WAITN(18);                                       \
    else if ((t) == 29)      WAITN(12);                                       \
    else if ((t) == 30)      WAITN(6);                                        \
    else if ((t) == 31)      WAITN(0);                                        \
    else if (((t) & 1) || (t) == 2 || (t) == 28) WAITN(22);                   \
    else                     WAITN(26);                                       \
    {                                                                         \
        const char* xb = wbase + (((t) >> 1) % 3) * 4096;                     \
        const float4 a0 = *(const float4*)(xb + r31 * 128 +                   \
            (((((t) & 1) * 4 + 2 * l5 + 0) ^ swr) << 4));                     \
        const float4 a1 = *(const float4*)(xb + r31 * 128 +                   \
            (((((t) & 1) * 4 + 2 * l5 + 1) ^ swr) << 4));                     \
        short8 H, M, L;                                                       \
        split3(a0, a1, H, M, L);                                              \
        acc0 = mfma6w(H, M, L, as_s8(w0v[(t)&3][0]), as_s8(w0v[(t)&3][1]),    \
                      as_s8(w0v[(t)&3][2]), acc0);                            \
        acc1 = mfma6w(H, M, L, as_s8(w1v[(t)&3][0]), as_s8(w1v[(t)&3][1]),    \
                      as_s8(w1v[(t)&3][2]), acc1);                            \
    }                                                                         \
    if (((t) & 1) && (t) <= 25) STAGE_CHUNK(((t) + 5) >> 1);                  \
} while (0)

    SLICE(0);  SLICE(1);  SLICE(2);  SLICE(3);
    SLICE(4);  SLICE(5);  SLICE(6);  SLICE(7);
    SLICE(8);  SLICE(9);  SLICE(10); SLICE(11);
    SLICE(12); SLICE(13); SLICE(14); SLICE(15);
    SLICE(16); SLICE(17); SLICE(18); SLICE(19);
    SLICE(20); SLICE(21); SLICE(22); SLICE(23);
    SLICE(24); SLICE(25); SLICE(26); SLICE(27);
    SLICE(28); SLICE(29); SLICE(30); SLICE(31);

    __syncthreads();
    float* lg = (float*)smem8;
#pragma unroll
    for (int r = 0; r < 16; ++r) {
        const int rowc = (r & 3) + 8 * (r >> 2) + 4 * l5;
        const int trow = 32 * tw + rowc;
        lg[(kq * 64 + trow) * (NE + 1) + r31]      = acc0[r];
        lg[(kq * 64 + trow) * (NE + 1) + 32 + r31] = acc1[r];
    }
    __syncthreads();
#pragma unroll
    for (int rr = 0; rr < 8; ++rr) {
        const int idx = tid + rr * 512;
        const int t = idx >> 6, e = idx & 63;
        lg[t * (NE + 1) + e] =
            (lg[t * (NE + 1) + e] + lg[(64 + t) * (NE + 1) + e]) +
            (lg[(128 + t) * (NE + 1) + e] + lg[(192 + t) * (NE + 1) + e]);
    }
    __syncthreads();
    if (tid < 64) {
        const float* rowp = lg + tid * (NE + 1);
        float mx = -3.402823466e38f;
        for (int e = 0; e < NE; ++e) mx = fmaxf(mx, rowp[e]);
        float sden = 0.f;
        for (int e = 0; e < NE; ++e) sden += expf(rowp[e] - mx);
        float tv[TOPKK]; int ti[TOPKK];
#pragma unroll
        for (int i = 0; i < TOPKK; ++i) { tv[i] = -3.402823466e38f; ti[i] = 0; }
        for (int e = 0; e < NE; ++e) {
            const float v = rowp[e];
            if (v > tv[TOPKK - 1]) {
                tv[TOPKK - 1] = v; ti[TOPKK - 1] = e;
#pragma unroll
                for (int q = TOPKK - 1; q > 0; --q) {
                    if (tv[q] > tv[q - 1]) {
                        const float fv = tv[q]; tv[q] = tv[q - 1]; tv[q - 1] = fv;
                        const int   iv = ti[q]; ti[q] = ti[q - 1]; ti[q - 1] = iv;
                    }
                }
            }
        }
        float* ow = out + (size_t)(bt0 + tid) * TOPKK;
        float* oi = out + (size_t)NT * TOPKK + (size_t)(bt0 + tid) * TOPKK;
#pragma unroll
        for (int i = 0; i < TOPKK; ++i) {
            ow[i] = expf(tv[i] - mx) / sden;
            oi[i] = (float)ti[i];
        }
    }
#undef SLICE
#undef STAGE_CHUNK
}

extern "C" void kernel_launch(void* const* d_in, const int* in_sizes, int n_in,
                              void* d_out, int out_size, void* d_ws, size_t ws_size,
                              hipStream_t stream) {
    const float* x = (const float*)d_in[0];
    const float* W = (const float*)d_in[1];
    float* out = (float*)d_out;
    short* wpk = (short*)d_ws;
    if (ws_size >= (size_t)WS_NEED) {
        float* pl = (float*)((char*)d_ws + WPK_BYTES);
        hipLaunchKernelGGL(pack_w_kernel, dim3(256), dim3(64), 0, stream, W, wpk);
        hipLaunchKernelGGL(gate_ksplit2_kernel, dim3(256), dim3(512),
                           KS2_LDS, stream, x, wpk, pl);
        hipLaunchKernelGGL(gate_combine_kernel, dim3(NT / 128), dim3(128), 0, stream,
                           pl, out);
    } else if (ws_size >= (size_t)WPK_BYTES) {
        hipLaunchKernelGGL(pack_w_kernel, dim3(256), dim3(64), 0, stream, W, wpk);
        hipLaunchKernelGGL(gate_main_r8, dim3(NT / 64), dim3(512), 0, stream,
                           x, wpk, out);
    }
}

// Round 12
// 54.694 us; speedup vs baseline: 1.1268x; 1.0442x over previous
//
#include <hip/hip_runtime.h>

// MoE gate: logits = x @ W^T (x:[16384,2048] f32, W:[64,2048] f32),
// softmax over 64 experts, top-8 -> weights f32 + indices stored as f32.
//
// R12: R8's proven barrier-free design at 2 blocks/CU (TLP hypothesis).
//  - TT=32, grid 512, 256 thr = 4 waves; wave = 32tok x 64exp x K/4
//    (R8's per-wave code verbatim, tw removed). LDS 48KB -> 2-3 blocks/CU.
//  - x: wave-private 3-deep LDS chunks via global_load_lds (128B runs,
//    granule-XOR source + matching XOR ds_read). W: packed bf16 H/M/L
//    triples from d_ws (L2-hot), register depth-3, FIFO-audited vmcnt.
//  - NO barriers in the K-loop; one __syncthreads before the fused
//    4-way combine + softmax + top-8 epilogue.
//  - mfma_f32_32x32x16_bf16, 6-product exact split ~= fp32 (HW-verified).

typedef __attribute__((ext_vector_type(8))) short short8;
typedef __attribute__((ext_vector_type(16))) float f32x16;
typedef __attribute__((ext_vector_type(4))) float f32x4;
typedef __attribute__((ext_vector_type(4))) unsigned int u32x4;

#define NT    16384
#define DIMK  2048
#define NE    64
#define TOPKK 8
#define TT    32
#define WPK_BYTES 786432

union U4S8 { unsigned int u[4]; short8 s; u32x4 v; };

__device__ __forceinline__ short8 as_s8(u32x4 v) { U4S8 t; t.v = v; return t.s; }

// Bit-exact 3-way bf16 split of 8 f32 (truncation; subtractions exact).
__device__ __forceinline__ void split3(const float4 a, const float4 b,
                                       short8& H, short8& M, short8& L) {
    const float f[8] = {a.x, a.y, a.z, a.w, b.x, b.y, b.z, b.w};
    U4S8 uh, um, ul;
#pragma unroll
    for (int p = 0; p < 4; ++p) {
        const float f0 = f[2 * p], f1 = f[2 * p + 1];
        const unsigned int t0 = __float_as_uint(f0) & 0xFFFF0000u;
        const unsigned int t1 = __float_as_uint(f1) & 0xFFFF0000u;
        uh.u[p] = (t0 >> 16) | t1;
        const float r0 = f0 - __uint_as_float(t0);
        const float r1 = f1 - __uint_as_float(t1);
        const unsigned int v0 = __float_as_uint(r0) & 0xFFFF0000u;
        const unsigned int v1 = __float_as_uint(r1) & 0xFFFF0000u;
        um.u[p] = (v0 >> 16) | v1;
        const float s0 = r0 - __uint_as_float(v0);
        const float s1 = r1 - __uint_as_float(v1);
        ul.u[p] = (__float_as_uint(s0) >> 16) | (__float_as_uint(s1) & 0xFFFF0000u);
    }
    H = uh.s; M = um.s; L = ul.s;
}

__device__ __forceinline__ f32x16 mfma6w(short8 ah, short8 am, short8 al,
                                         short8 bh, short8 bm, short8 bl,
                                         f32x16 c) {
    c = __builtin_amdgcn_mfma_f32_32x32x16_bf16(ah, bh, c, 0, 0, 0);
    c = __builtin_amdgcn_mfma_f32_32x32x16_bf16(ah, bm, c, 0, 0, 0);
    c = __builtin_amdgcn_mfma_f32_32x32x16_bf16(am, bh, c, 0, 0, 0);
    c = __builtin_amdgcn_mfma_f32_32x32x16_bf16(ah, bl, c, 0, 0, 0);
    c = __builtin_amdgcn_mfma_f32_32x32x16_bf16(am, bm, c, 0, 0, 0);
    c = __builtin_amdgcn_mfma_f32_32x32x16_bf16(al, bh, c, 0, 0, 0);
    return c;
}

// ---- pack W -> 32x32 B-fragment bf16 triples (HW-verified R5/R7/R8) ----
__global__ __launch_bounds__(64) void pack_w_kernel(
    const float* __restrict__ W, short* __restrict__ wpk)
{
    const int b  = blockIdx.x;          // 256 = c*8 + fg, fg = 2*s16 + n32
    const int c  = b >> 3, fg = b & 7;
    const int s  = fg >> 1, n32 = fg & 1;
    const int l  = threadIdx.x;
    const float* g = W + (size_t)(32 * n32 + (l & 31)) * DIMK
                       + 64 * c + 16 * s + 8 * (l >> 5);
    const float4 lo = *(const float4*)g;
    const float4 hi = *(const float4*)(g + 4);
    short8 H, M, L;
    split3(lo, hi, H, M, L);
    const size_t base = ((size_t)(c * 8 + fg) * 3) * 512 + l * 8;
    *(short8*)(wpk + base)        = H;
    *(short8*)(wpk + base + 512)  = M;
    *(short8*)(wpk + base + 1024) = L;
}

#define WLOAD3(d0, d1, d2, p)                                                 \
    asm volatile("global_load_dwordx4 %0, %3, off\n\t"                        \
                 "global_load_dwordx4 %1, %3, off offset:1024\n\t"            \
                 "global_load_dwordx4 %2, %3, off offset:2048"                \
                 : "=&v"(d0), "=&v"(d1), "=&v"(d2) : "v"(p))
#define WAITN(n) do {                                                         \
    asm volatile("s_waitcnt vmcnt(" #n ")" ::: "memory");                     \
    __builtin_amdgcn_sched_barrier(0);                                        \
} while (0)

__device__ __forceinline__ void async16(void* lds, const void* gp) {
    __builtin_amdgcn_global_load_lds(
        (const __attribute__((address_space(1))) unsigned int*)gp,
        (__attribute__((address_space(3))) unsigned int*)lds, 16, 0, 0);
}

// ================= R12 main: 4-wave blocks, 2 blocks/CU =================
__global__ __launch_bounds__(256, 2) void gate_main_r12(
    const float* __restrict__ x, const short* __restrict__ wpk,
    float* __restrict__ out)
{
    // 4 waves x 3 bufs x 4KB = 48KB wave-private staging; lg aliases it.
    __shared__ __align__(16) char smem[4 * 3 * 4096];

    const int tid = threadIdx.x;
    const int w   = tid >> 6;       // 4 waves; kq = w (K quarter)
    const int l   = tid & 63;
    const int r31 = l & 31;
    const int l5  = l >> 5;
    const int kq  = w;
    const int bt0 = blockIdx.x * TT;

    char* wbase = smem + w * 12288;
    const int swr = (r31 & 7) ^ (((r31 >> 3) & 3) << 1);
    const int srow = l >> 3;
    const int sg0  = (l & 7) ^ srow;
    const float* xrow0 = x + (size_t)(bt0 + srow) * DIMK + kq * 512;

#define STAGE_CHUNK(k) do {                                                   \
    _Pragma("unroll")                                                         \
    for (int i = 0; i < 4; ++i) {                                             \
        const float* gsrc = xrow0 + (size_t)(8 * i) * DIMK + (k) * 32         \
                          + ((sg0 ^ (2 * i)) << 2);                           \
        async16(wbase + ((k) % 3) * 4096 + i * 1024, gsrc);                   \
    }                                                                         \
} while (0)

    const short* wq0 = wpk + (size_t)kq * 98304 + l * 8;
    const short* wq1 = wq0 + 1536;
    f32x16 acc0, acc1;
#pragma unroll
    for (int i = 0; i < 16; ++i) { acc0[i] = 0.f; acc1[i] = 0.f; }
    u32x4 w0v[4][3], w1v[4][3];

    STAGE_CHUNK(0); STAGE_CHUNK(1); STAGE_CHUNK(2);
    WLOAD3(w0v[0][0], w0v[0][1], w0v[0][2], wq0); wq0 += 3072;
    WLOAD3(w1v[0][0], w1v[0][1], w1v[0][2], wq1); wq1 += 3072;
    WLOAD3(w0v[1][0], w0v[1][1], w0v[1][2], wq0); wq0 += 3072;
    WLOAD3(w1v[1][0], w1v[1][1], w1v[1][2], wq1); wq1 += 3072;
    WLOAD3(w0v[2][0], w0v[2][1], w0v[2][2], wq0); wq0 += 3072;
    WLOAD3(w1v[2][0], w1v[2][1], w1v[2][2], wq1); wq1 += 3072;

    // R8's HW-proven schedule, verbatim literals (per-wave FIFO identical).
#define SLICE(t) do {                                                         \
    if ((t) <= 28) {                                                          \
        WLOAD3(w0v[((t)+3)&3][0], w0v[((t)+3)&3][1], w0v[((t)+3)&3][2], wq0); \
        wq0 += 3072;                                                          \
        WLOAD3(w1v[((t)+3)&3][0], w1v[((t)+3)&3][1], w1v[((t)+3)&3][2], wq1); \
        wq1 += 3072;                                                          \
    }                                                                         \
    if ((t) <= 1)            WAITN(18);                                       \
    else if ((t) == 29)      WAITN(12);                                       \
    else if ((t) == 30)      WAITN(6);                                        \
    else if ((t) == 31)      WAITN(0);                                        \
    else if (((t) & 1) || (t) == 2 || (t) == 28) WAITN(22);                   \
    else                     WAITN(26);                                       \
    {                                                                         \
        const char* xb = wbase + (((t) >> 1) % 3) * 4096;                     \
        const float4 a0 = *(const float4*)(xb + r31 * 128 +                   \
            (((((t) & 1) * 4 + 2 * l5 + 0) ^ swr) << 4));                     \
        const float4 a1 = *(const float4*)(xb + r31 * 128 +                   \
            (((((t) & 1) * 4 + 2 * l5 + 1) ^ swr) << 4));                     \
        short8 H, M, L;                                                       \
        split3(a0, a1, H, M, L);                                              \
        acc0 = mfma6w(H, M, L, as_s8(w0v[(t)&3][0]), as_s8(w0v[(t)&3][1]),    \
                      as_s8(w0v[(t)&3][2]), acc0);                            \
        acc1 = mfma6w(H, M, L, as_s8(w1v[(t)&3][0]), as_s8(w1v[(t)&3][1]),    \
                      as_s8(w1v[(t)&3][2]), acc1);                            \
    }                                                                         \
    if (((t) & 1) && (t) <= 25) STAGE_CHUNK(((t) + 5) >> 1);                  \
} while (0)

    SLICE(0);  SLICE(1);  SLICE(2);  SLICE(3);
    SLICE(4);  SLICE(5);  SLICE(6);  SLICE(7);
    SLICE(8);  SLICE(9);  SLICE(10); SLICE(11);
    SLICE(12); SLICE(13); SLICE(14); SLICE(15);
    SLICE(16); SLICE(17); SLICE(18); SLICE(19);
    SLICE(20); SLICE(21); SLICE(22); SLICE(23);
    SLICE(24); SLICE(25); SLICE(26); SLICE(27);
    SLICE(28); SLICE(29); SLICE(30); SLICE(31);

    __syncthreads();   // all staging reads done; lg aliases staging LDS

    // partials -> lg[kq][32][65]; C/D: col=l&31, row=(r&3)+8*(r>>2)+4*l5
    float* lg = (float*)smem;
#pragma unroll
    for (int r = 0; r < 16; ++r) {
        const int rowc = (r & 3) + 8 * (r >> 2) + 4 * l5;
        lg[(w * TT + rowc) * (NE + 1) + r31]      = acc0[r];
        lg[(w * TT + rowc) * (NE + 1) + 32 + r31] = acc1[r];
    }
    __syncthreads();

    // deterministic 4-way K reduction: 2048 entries / 256 thr
#pragma unroll
    for (int rr = 0; rr < (TT * NE) / 256; ++rr) {
        const int idx = tid + rr * 256;
        const int t = idx >> 6, e = idx & 63;
        lg[t * (NE + 1) + e] =
            (lg[t * (NE + 1) + e] + lg[(TT + t) * (NE + 1) + e]) +
            (lg[(2 * TT + t) * (NE + 1) + e] + lg[(3 * TT + t) * (NE + 1) + e]);
    }
    __syncthreads();

    // fused softmax + top-8: one lane per token
    if (tid < TT) {
        const float* rowp = lg + tid * (NE + 1);
        float mx = -3.402823466e38f;
        for (int e = 0; e < NE; ++e) mx = fmaxf(mx, rowp[e]);
        float sden = 0.f;
        for (int e = 0; e < NE; ++e) sden += expf(rowp[e] - mx);

        float tv[TOPKK];
        int   ti[TOPKK];
#pragma unroll
        for (int i = 0; i < TOPKK; ++i) { tv[i] = -3.402823466e38f; ti[i] = 0; }
        for (int e = 0; e < NE; ++e) {
            const float v = rowp[e];
            if (v > tv[TOPKK - 1]) {
                tv[TOPKK - 1] = v; ti[TOPKK - 1] = e;
#pragma unroll
                for (int q = TOPKK - 1; q > 0; --q) {
                    if (tv[q] > tv[q - 1]) {
                        const float fv = tv[q]; tv[q] = tv[q - 1]; tv[q - 1] = fv;
                        const int   iv = ti[q]; ti[q] = ti[q - 1]; ti[q - 1] = iv;
                    }
                }
            }
        }
        float* ow = out + (size_t)(bt0 + tid) * TOPKK;
        float* oi = out + (size_t)NT * TOPKK + (size_t)(bt0 + tid) * TOPKK;
#pragma unroll
        for (int i = 0; i < TOPKK; ++i) {
            ow[i] = expf(tv[i] - mx) / sden;   // ROUTE_SCALE == 1.0
            oi[i] = (float)ti[i];
        }
    }
#undef SLICE
#undef STAGE_CHUNK
}

// ================= fallback (no-ws): R2-style reg-direct kernel ===========
__device__ __forceinline__ f32x4 mfma6s(short8 ah, short8 am, short8 al,
                                        short8 bh, short8 bm, short8 bl, f32x4 c) {
    c = __builtin_amdgcn_mfma_f32_16x16x32_bf16(ah, bh, c, 0, 0, 0);
    c = __builtin_amdgcn_mfma_f32_16x16x32_bf16(ah, bm, c, 0, 0, 0);
    c = __builtin_amdgcn_mfma_f32_16x16x32_bf16(am, bh, c, 0, 0, 0);
    c = __builtin_amdgcn_mfma_f32_16x16x32_bf16(ah, bl, c, 0, 0, 0);
    c = __builtin_amdgcn_mfma_f32_16x16x32_bf16(am, bm, c, 0, 0, 0);
    c = __builtin_amdgcn_mfma_f32_16x16x32_bf16(al, bh, c, 0, 0, 0);
    return c;
}

__device__ __forceinline__ void load_step(const float* xp0, const float* xp1,
                                          const float* wp, int koff,
                                          float4 xb[2][2], float4 wb[4][2]) {
#pragma unroll
    for (int h = 0; h < 2; ++h) {
        xb[0][h] = *(const float4*)(xp0 + koff + 4 * h);
        xb[1][h] = *(const float4*)(xp1 + koff + 4 * h);
    }
#pragma unroll
    for (int n = 0; n < 4; ++n)
#pragma unroll
        for (int h = 0; h < 2; ++h)
            wb[n][h] = *(const float4*)(wp + (size_t)n * 16 * DIMK + koff + 4 * h);
}

__device__ __forceinline__ void do_step(const float4 xc[2][2], const float4 wc[4][2],
                                        f32x4 acc[2][4]) {
    short8 ah[2], am[2], al[2];
#pragma unroll
    for (int m = 0; m < 2; ++m) split3(xc[m][0], xc[m][1], ah[m], am[m], al[m]);
#pragma unroll
    for (int n = 0; n < 4; ++n) {
        short8 bh, bm, bl;
        split3(wc[n][0], wc[n][1], bh, bm, bl);
#pragma unroll
        for (int m = 0; m < 2; ++m)
            acc[m][n] = mfma6s(ah[m], am[m], al[m], bh, bm, bl, acc[m][n]);
    }
}

__global__ __launch_bounds__(256, 2) void gate_fallback_kernel(
    const float* __restrict__ x, const float* __restrict__ W,
    float* __restrict__ out)
{
    __shared__ float lg[4][32][NE + 1];
    const int tid = threadIdx.x;
    const int w = tid >> 6, l = tid & 63;
    const int j = l & 15, g = l >> 4;
    const int bt0 = blockIdx.x * 32;
    const int kb = w * 512;
    const float* xp0 = x + (size_t)(bt0 + j) * DIMK + kb + 8 * g;
    const float* xp1 = xp0 + (size_t)16 * DIMK;
    const float* wpp = W + (size_t)j * DIMK + kb + 8 * g;
    f32x4 acc[2][4];
#pragma unroll
    for (int m = 0; m < 2; ++m)
#pragma unroll
        for (int n = 0; n < 4; ++n) acc[m][n] = (f32x4){0.f, 0.f, 0.f, 0.f};
    float4 xA[2][2], wA[4][2], xB[2][2], wB[4][2];
    load_step(xp0, xp1, wpp, 0, xA, wA);
#pragma unroll 1
    for (int s = 0; s < 16; s += 2) {
        load_step(xp0, xp1, wpp, 32 * (s + 1), xB, wB);
        do_step(xA, wA, acc);
        if (s + 2 < 16) load_step(xp0, xp1, wpp, 32 * (s + 2), xA, wA);
        do_step(xB, wB, acc);
    }
#pragma unroll
    for (int m = 0; m < 2; ++m)
#pragma unroll
        for (int n = 0; n < 4; ++n)
#pragma unroll
            for (int q = 0; q < 4; ++q)
                lg[w][16 * m + 4 * g + q][16 * n + j] = acc[m][n][q];
    __syncthreads();
#pragma unroll
    for (int r = 0; r < 8; ++r) {
        const int idx = tid + r * 256;
        const int t = idx >> 6, e = idx & 63;
        lg[0][t][e] += lg[1][t][e] + lg[2][t][e] + lg[3][t][e];
    }
    __syncthreads();
    if (tid < 32) {
        const float* rowp = &lg[0][tid][0];
        float mx = -3.402823466e38f;
        for (int e = 0; e < NE; ++e) mx = fmaxf(mx, rowp[e]);
        float sden = 0.f;
        for (int e = 0; e < NE; ++e) sden += expf(rowp[e] - mx);
        float tv[TOPKK]; int ti[TOPKK];
#pragma unroll
        for (int i = 0; i < TOPKK; ++i) { tv[i] = -3.402823466e38f; ti[i] = 0; }
        for (int e = 0; e < NE; ++e) {
            const float v = rowp[e];
            if (v > tv[TOPKK - 1]) {
                tv[TOPKK - 1] = v; ti[TOPKK - 1] = e;
#pragma unroll
                for (int q = TOPKK - 1; q > 0; --q)
                    if (tv[q] > tv[q - 1]) {
                        const float fv = tv[q]; tv[q] = tv[q - 1]; tv[q - 1] = fv;
                        const int iv = ti[q]; ti[q] = ti[q - 1]; ti[q - 1] = iv;
                    }
            }
        }
        float* ow = out + (size_t)(bt0 + tid) * TOPKK;
        float* oi = out + (size_t)NT * TOPKK + (size_t)(bt0 + tid) * TOPKK;
#pragma unroll
        for (int i = 0; i < TOPKK; ++i) {
            ow[i] = expf(tv[i] - mx) / sden;
            oi[i] = (float)ti[i];
        }
    }
}

extern "C" void kernel_launch(void* const* d_in, const int* in_sizes, int n_in,
                              void* d_out, int out_size, void* d_ws, size_t ws_size,
                              hipStream_t stream) {
    const float* x = (const float*)d_in[0];
    const float* W = (const float*)d_in[1];
    float* out = (float*)d_out;
    if (ws_size >= (size_t)WPK_BYTES) {
        short* wpk = (short*)d_ws;
        hipLaunchKernelGGL(pack_w_kernel, dim3(256), dim3(64), 0, stream, W, wpk);
        hipLaunchKernelGGL(gate_main_r12, dim3(NT / TT), dim3(256), 0, stream,
                           x, wpk, out);
    } else {
        hipLaunchKernelGGL(gate_fallback_kernel, dim3(NT / 32), dim3(256), 0, stream,
                           x, W, out);
    }
}